// Round 2
// baseline (1360.838 us; speedup 1.0000x reference)
//
#include <hip/hip_runtime.h>

#define N_ROWS 262144
#define DIM 64
#define KCODES 512
#define TAU 1e-2f   // fp32 noise ~1e-5 on dist ~85; 1000x safety margin

// -------- init: transpose codebook into ws, precompute e2 (f32+f64), zero loss
// ws layout: eT[KCODES*DIM] f32 | e2f[KCODES] f32 | e2d[KCODES] f64 (8B aligned)
__global__ void vq_init(const float* __restrict__ e, float* __restrict__ eT,
                        float* __restrict__ e2f, double* __restrict__ e2d,
                        float* __restrict__ loss_slot) {
    int idx = blockIdx.x * blockDim.x + threadIdx.x;   // grid covers 32768
    if (idx < KCODES * DIM) {
        int k = idx >> 6;    // / DIM
        int d = idx & (DIM - 1);
        eT[idx] = e[d * KCODES + k];
    }
    if (idx < KCODES) {
        double s = 0.0;
        for (int d = 0; d < DIM; ++d) {
            double v = (double)e[d * KCODES + idx];
            s = fma(v, v, s);
        }
        e2d[idx] = s;
        e2f[idx] = (float)s;
    }
    if (idx == 0) *loss_slot = 0.f;
}

__global__ void vq_zero_loss(float* __restrict__ loss_slot) {
    *loss_slot = 0.f;
}

// -------- main: one thread per row ------------------------------------------
template <bool USE_WS>
__global__ __launch_bounds__(256) void vq_main(
    const float* __restrict__ x,
    const float* __restrict__ e,     // original [D, K] layout (fallback path)
    const float* __restrict__ eT,    // transposed [K, D] (USE_WS path)
    const float* __restrict__ e2fg,  // f32 e2 (USE_WS path)
    const double* __restrict__ e2dg, // f64 e2 (USE_WS path)
    float* __restrict__ out,
    float* __restrict__ loss_slot) {

    __shared__ float e2s[KCODES];   // fallback: per-block f32 e2
    if (!USE_WS) {
        for (int k = threadIdx.x; k < KCODES; k += blockDim.x) {
            float s = 0.f;
            for (int d = 0; d < DIM; ++d) {
                float v = e[d * KCODES + k];
                s = fmaf(v, v, s);
            }
            e2s[k] = s;
        }
        __syncthreads();
    }

    const int row = blockIdx.x * 256 + threadIdx.x;   // grid exactly covers N
    const float* xr = x + (size_t)row * DIM;

    float xv[DIM];
    #pragma unroll
    for (int j = 0; j < DIM / 4; ++j) {
        float4 v = ((const float4*)xr)[j];
        xv[4 * j + 0] = v.x;
        xv[4 * j + 1] = v.y;
        xv[4 * j + 2] = v.z;
        xv[4 * j + 3] = v.w;
    }

    float x2 = 0.f;
    #pragma unroll
    for (int d = 0; d < DIM; ++d) x2 = fmaf(xv[d], xv[d], x2);

    // ---- fast fp32 pass: best + second-best ----
    float best = 3.4e38f, second = 3.4e38f;
    int bestk = 0;

    for (int k = 0; k < KCODES; ++k) {
        float dot = 0.f;
        if (USE_WS) {
            const float* ek = eT + k * DIM;           // contiguous, wave-uniform
            #pragma unroll
            for (int d = 0; d < DIM; ++d) dot = fmaf(xv[d], ek[d], dot);
        } else {
            const float* ek = e + k;                  // stride-K, wave-uniform
            #pragma unroll
            for (int d = 0; d < DIM; ++d) dot = fmaf(xv[d], ek[d * KCODES], dot);
        }
        const float e2k = USE_WS ? e2fg[k] : e2s[k];
        const float dist = fmaf(-2.f, dot, x2 + e2k);
        if (dist < best) { second = best; best = dist; bestk = k; }
        else if (dist < second) { second = dist; }
    }

    float bestval = best;

    // ---- rare fp64 rescan when the fp32 margin can't certify the argmin ----
    if (second - best < TAU) {
        double x2d = 0.0;
        #pragma unroll
        for (int d = 0; d < DIM; ++d)
            x2d = fma((double)xv[d], (double)xv[d], x2d);

        double bestd = 1e300;
        int bk = 0;
        for (int k = 0; k < KCODES; ++k) {
            double dot = 0.0;
            double e2k;
            if (USE_WS) {
                const float* ek = eT + k * DIM;
                #pragma unroll
                for (int d = 0; d < DIM; ++d)
                    dot = fma((double)xv[d], (double)ek[d], dot);
                e2k = e2dg[k];
            } else {
                const float* ek = e + k;
                double e2acc = 0.0;
                #pragma unroll
                for (int d = 0; d < DIM; ++d) {
                    double v = (double)ek[d * KCODES];
                    dot = fma((double)xv[d], v, dot);
                    e2acc = fma(v, v, e2acc);
                }
                e2k = e2acc;
            }
            const double dist = fma(-2.0, dot, x2d + e2k);
            if (dist < bestd) { bestd = dist; bk = k; }  // strict < = first index
        }
        bestk = bk;
        bestval = (float)bestd;
    }

    // ---- write quantized row (= straight-through output value) ----
    float4* o4 = (float4*)(out + (size_t)row * DIM);
    if (USE_WS) {
        const float4* q4 = (const float4*)(eT + bestk * DIM);
        #pragma unroll
        for (int j = 0; j < DIM / 4; ++j) o4[j] = q4[j];
    } else {
        #pragma unroll
        for (int j = 0; j < DIM / 4; ++j) {
            float4 v;
            v.x = e[(4 * j + 0) * KCODES + bestk];
            v.y = e[(4 * j + 1) * KCODES + bestk];
            v.z = e[(4 * j + 2) * KCODES + bestk];
            v.w = e[(4 * j + 3) * KCODES + bestk];
            o4[j] = v;
        }
    }

    // ---- loss: sum of per-row min distances (== sum (q-x)^2) ----
    __shared__ float red[256];
    red[threadIdx.x] = bestval;
    __syncthreads();
    #pragma unroll
    for (int s = 128; s > 0; s >>= 1) {
        if (threadIdx.x < s) red[threadIdx.x] += red[threadIdx.x + s];
        __syncthreads();
    }
    if (threadIdx.x == 0) {
        // loss = 1.25 * mean((q-x)^2) over N*D elements
        atomicAdd(loss_slot, red[0] * (1.25f / ((float)N_ROWS * (float)DIM)));
    }
}

extern "C" void kernel_launch(void* const* d_in, const int* in_sizes, int n_in,
                              void* d_out, int out_size, void* d_ws, size_t ws_size,
                              hipStream_t stream) {
    const float* x = (const float*)d_in[0];   // [N, D]
    const float* e = (const float*)d_in[1];   // [D, K]
    float* out = (float*)d_out;               // N*D quantized + 1 loss
    float* loss_slot = out + (size_t)N_ROWS * DIM;

    const size_t ws_needed =
        (size_t)(KCODES * DIM + KCODES) * sizeof(float) + KCODES * sizeof(double);
    const int nblocks = N_ROWS / 256;

    if (ws_size >= ws_needed) {
        float* eT = (float*)d_ws;
        float* e2f = eT + KCODES * DIM;
        double* e2d = (double*)(e2f + KCODES);   // 8-byte aligned (offset 133120)
        vq_init<<<(KCODES * DIM + 255) / 256, 256, 0, stream>>>(e, eT, e2f, e2d, loss_slot);
        vq_main<true><<<nblocks, 256, 0, stream>>>(x, e, eT, e2f, e2d, out, loss_slot);
    } else {
        vq_zero_loss<<<1, 1, 0, stream>>>(loss_slot);
        vq_main<false><<<nblocks, 256, 0, stream>>>(x, e, nullptr, nullptr, nullptr, out, loss_slot);
    }
}

// Round 3
// 539.840 us; speedup vs baseline: 2.5208x; 2.5208x over previous
//
#include <hip/hip_runtime.h>

#define N_ROWS 262144
#define DIM 64
#define KCODES 512
#define KTILE 128
#define KSTRIDE 68      // 64 code dims + e2 at [64] + 3 pad; 272 B = 17*16 (16B aligned)
#define TAU 4e-3f       // worst-case fp32 dist err ~5e-4/dist; pair ~1e-3; 4x margin

// -------- init: transpose codebook into ws [K][D], precompute e2 (f32), zero loss
__global__ void vq_init(const float* __restrict__ e, float* __restrict__ eT,
                        float* __restrict__ e2f, float* __restrict__ loss_slot) {
    int idx = blockIdx.x * blockDim.x + threadIdx.x;   // grid covers 32768
    if (idx < KCODES * DIM) {
        int k = idx >> 6;
        int d = idx & (DIM - 1);
        eT[idx] = e[d * KCODES + k];
    }
    if (idx < KCODES) {
        double s = 0.0;
        for (int d = 0; d < DIM; ++d) {
            double v = (double)e[d * KCODES + idx];
            s = fma(v, v, s);
        }
        e2f[idx] = (float)s;
    }
    if (idx == 0) *loss_slot = 0.f;
}

__global__ void vq_zero_loss(float* __restrict__ loss_slot) {
    *loss_slot = 0.f;
}

// -------- wave-cooperative exact (fp64) rescan of one row ------------------
// Called by ALL 64 lanes of the wave (uniform control flow). Lane l covers
// codes k = l + 64j. Returns the fp64 argmin (first-occurrence ties) + value.
__device__ inline void wave_rescan(const float* __restrict__ x,
                                   const float* __restrict__ e,  // [D][K]
                                   int row, double* outDist, int* outK) {
    const int lane = threadIdx.x & 63;
    const float* xr = x + (size_t)row * DIM;

    double x2d = 0.0;
    for (int d = 0; d < DIM; ++d) {
        double xd = (double)xr[d];
        x2d = fma(xd, xd, x2d);
    }

    double best = 1e300;
    int bk = 0;
    for (int j = 0; j < 8; ++j) {
        const int k = lane + (j << 6);
        double dot = 0.0, e2 = 0.0;
        for (int d = 0; d < DIM; ++d) {
            double xd = (double)xr[d];
            double ev = (double)e[d * KCODES + k];   // consecutive lanes coalesced
            dot = fma(xd, ev, dot);
            e2 = fma(ev, ev, e2);
        }
        double dist = fma(-2.0, dot, x2d + e2);
        if (dist < best) { best = dist; bk = k; }    // ascending k per lane
    }
    // butterfly argmin reduce; tie -> smaller k (first occurrence)
    #pragma unroll
    for (int off = 32; off; off >>= 1) {
        double od = __shfl_xor(best, off);
        int ok = __shfl_xor(bk, off);
        if (od < best || (od == best && ok < bk)) { best = od; bk = ok; }
    }
    *outDist = best;
    *outK = bk;
}

// -------- main: 2 rows per thread, LDS-broadcast codebook tiles -------------
template <bool USE_WS>
__global__ __launch_bounds__(256, 2) void vq_main(
    const float* __restrict__ x,
    const float* __restrict__ e,     // [D][K] original layout
    const float* __restrict__ eT,    // [K][D] transposed (USE_WS)
    const float* __restrict__ e2fg,  // e2 f32 (USE_WS)
    float* __restrict__ out,
    float* __restrict__ loss_slot) {

    __shared__ float sh[KTILE * KSTRIDE];   // 34816 B
    __shared__ float red[256];

    const int tid = threadIdx.x;
    const int blockBase = blockIdx.x * 512;
    const int r0 = blockBase + tid;
    const int r1 = r0 + 256;

    // ---- load the 2 x-rows into registers ----
    float xa[DIM], xb[DIM];
    {
        const float4* xr0 = (const float4*)(x + (size_t)r0 * DIM);
        const float4* xr1 = (const float4*)(x + (size_t)r1 * DIM);
        #pragma unroll
        for (int j = 0; j < DIM / 4; ++j) {
            float4 v0 = xr0[j];
            float4 v1 = xr1[j];
            xa[4*j+0]=v0.x; xa[4*j+1]=v0.y; xa[4*j+2]=v0.z; xa[4*j+3]=v0.w;
            xb[4*j+0]=v1.x; xb[4*j+1]=v1.y; xb[4*j+2]=v1.z; xb[4*j+3]=v1.w;
        }
    }

    float x2a, x2b;
    {
        float p0=0.f,p1=0.f,q0=0.f,q1=0.f;
        #pragma unroll
        for (int d = 0; d < DIM; d += 2) {
            p0 = fmaf(xa[d], xa[d], p0);
            p1 = fmaf(xa[d+1], xa[d+1], p1);
            q0 = fmaf(xb[d], xb[d], q0);
            q1 = fmaf(xb[d+1], xb[d+1], q1);
        }
        x2a = p0 + p1;
        x2b = q0 + q1;
    }

    float bestA = 3.4e38f, secA = 3.4e38f, bestB = 3.4e38f, secB = 3.4e38f;
    int bkA = 0, bkB = 0;

    for (int kb = 0; kb < KCODES; kb += KTILE) {
        // ---- stage tile (codes kb..kb+127) into LDS ----
        if (USE_WS) {
            for (int idx = tid; idx < KTILE * 17; idx += 256) {
                int c = idx / 17;
                int q = idx - c * 17;
                if (q < 16) {
                    float4 v = ((const float4*)(eT + (size_t)(kb + c) * DIM))[q];
                    *(float4*)(sh + c * KSTRIDE + q * 4) = v;
                } else {
                    sh[c * KSTRIDE + 64] = e2fg[kb + c];
                }
            }
        } else {
            for (int idx = tid; idx < KTILE * DIM; idx += 256) {
                int d = idx >> 7;             // 0..63
                int c = idx & (KTILE - 1);    // coalesced over c
                sh[c * KSTRIDE + d] = e[d * KCODES + kb + c];
            }
            __syncthreads();
            if (tid < KTILE) {
                float s = 0.f;
                for (int d = 0; d < DIM; ++d) {
                    float v = sh[tid * KSTRIDE + d];
                    s = fmaf(v, v, s);
                }
                sh[tid * KSTRIDE + 64] = s;
            }
        }
        __syncthreads();

        // ---- distance loop over the tile ----
        for (int k = 0; k < KTILE; ++k) {
            const float* ck = sh + k * KSTRIDE;
            float a0=0.f, a1=0.f, b0=0.f, b1=0.f;   // 4 independent chains
            #pragma unroll
            for (int j = 0; j < 16; j += 2) {
                float4 c0 = *(const float4*)(ck + 4 * j);
                float4 c1 = *(const float4*)(ck + 4 * j + 4);
                a0 = fmaf(xa[4*j+0], c0.x, a0);
                a0 = fmaf(xa[4*j+1], c0.y, a0);
                a0 = fmaf(xa[4*j+2], c0.z, a0);
                a0 = fmaf(xa[4*j+3], c0.w, a0);
                b0 = fmaf(xb[4*j+0], c0.x, b0);
                b0 = fmaf(xb[4*j+1], c0.y, b0);
                b0 = fmaf(xb[4*j+2], c0.z, b0);
                b0 = fmaf(xb[4*j+3], c0.w, b0);
                a1 = fmaf(xa[4*j+4], c1.x, a1);
                a1 = fmaf(xa[4*j+5], c1.y, a1);
                a1 = fmaf(xa[4*j+6], c1.z, a1);
                a1 = fmaf(xa[4*j+7], c1.w, a1);
                b1 = fmaf(xb[4*j+4], c1.x, b1);
                b1 = fmaf(xb[4*j+5], c1.y, b1);
                b1 = fmaf(xb[4*j+6], c1.z, b1);
                b1 = fmaf(xb[4*j+7], c1.w, b1);
            }
            const float e2k = ck[64];
            const int kg = kb + k;
            const float dA = fmaf(-2.f, a0 + a1, x2a + e2k);
            const float dB = fmaf(-2.f, b0 + b1, x2b + e2k);
            if (dA < bestA) { secA = bestA; bestA = dA; bkA = kg; }
            else if (dA < secA) { secA = dA; }
            if (dB < bestB) { secB = bestB; bestB = dB; bkB = kg; }
            else if (dB < secB) { secB = dB; }
        }
        __syncthreads();   // before next tile overwrites sh
    }

    // ---- rare wave-cooperative fp64 certify/rescan ----
    const int lane = tid & 63;
    const int waveBase = blockBase + (tid & ~63);
    {
        unsigned long long m = __ballot(secA - bestA < TAU);
        while (m) {
            int l = __builtin_ctzll((long long)m);
            m &= m - 1;
            double bd; int bk2;
            wave_rescan(x, e, waveBase + l, &bd, &bk2);
            if (lane == l) { bestA = (float)bd; bkA = bk2; }
        }
        m = __ballot(secB - bestB < TAU);
        while (m) {
            int l = __builtin_ctzll((long long)m);
            m &= m - 1;
            double bd; int bk2;
            wave_rescan(x, e, waveBase + 256 + l, &bd, &bk2);
            if (lane == l) { bestB = (float)bd; bkB = bk2; }
        }
    }

    // ---- write quantized rows ----
    {
        float4* o0 = (float4*)(out + (size_t)r0 * DIM);
        float4* o1 = (float4*)(out + (size_t)r1 * DIM);
        if (USE_WS) {
            const float4* qa = (const float4*)(eT + (size_t)bkA * DIM);
            const float4* qb = (const float4*)(eT + (size_t)bkB * DIM);
            #pragma unroll
            for (int j = 0; j < DIM / 4; ++j) { o0[j] = qa[j]; o1[j] = qb[j]; }
        } else {
            #pragma unroll
            for (int j = 0; j < DIM / 4; ++j) {
                float4 va, vb;
                va.x = e[(4*j+0) * KCODES + bkA]; vb.x = e[(4*j+0) * KCODES + bkB];
                va.y = e[(4*j+1) * KCODES + bkA]; vb.y = e[(4*j+1) * KCODES + bkB];
                va.z = e[(4*j+2) * KCODES + bkA]; vb.z = e[(4*j+2) * KCODES + bkB];
                va.w = e[(4*j+3) * KCODES + bkA]; vb.w = e[(4*j+3) * KCODES + bkB];
                o0[j] = va; o1[j] = vb;
            }
        }
    }

    // ---- loss: sum of per-row min distances == sum (q-x)^2 ----
    red[tid] = bestA + bestB;
    __syncthreads();
    #pragma unroll
    for (int s = 128; s > 0; s >>= 1) {
        if (tid < s) red[tid] += red[tid + s];
        __syncthreads();
    }
    if (tid == 0) {
        atomicAdd(loss_slot, red[0] * (1.25f / ((float)N_ROWS * (float)DIM)));
    }
}

extern "C" void kernel_launch(void* const* d_in, const int* in_sizes, int n_in,
                              void* d_out, int out_size, void* d_ws, size_t ws_size,
                              hipStream_t stream) {
    const float* x = (const float*)d_in[0];   // [N, D]
    const float* e = (const float*)d_in[1];   // [D, K]
    float* out = (float*)d_out;               // N*D quantized + 1 loss
    float* loss_slot = out + (size_t)N_ROWS * DIM;

    const size_t ws_needed = (size_t)(KCODES * DIM + KCODES) * sizeof(float);
    const int nblocks = N_ROWS / 512;         // 2 rows per thread

    if (ws_size >= ws_needed) {
        float* eT = (float*)d_ws;
        float* e2f = eT + KCODES * DIM;
        vq_init<<<(KCODES * DIM + 255) / 256, 256, 0, stream>>>(e, eT, e2f, loss_slot);
        vq_main<true><<<nblocks, 256, 0, stream>>>(x, e, eT, e2f, out, loss_slot);
    } else {
        vq_zero_loss<<<1, 1, 0, stream>>>(loss_slot);
        vq_main<false><<<nblocks, 256, 0, stream>>>(x, e, nullptr, nullptr, out, loss_slot);
    }
}

// Round 4
// 288.108 us; speedup vs baseline: 4.7234x; 1.8737x over previous
//
#include <hip/hip_runtime.h>

#define N_ROWS 262144
#define DIM 64
#define KCODES 512
#define TAU_MFMA 8e-3f   // bf16-split dist err worst ~2e-3, typical ~1e-4; 4x margin
#define TAU_SC   4e-3f   // fallback fp32 path (round-3 proven)

typedef __attribute__((ext_vector_type(8))) short bf16x8;
typedef __attribute__((ext_vector_type(4))) float f32x4;

static __device__ __forceinline__ short f2bf(float f) {   // RNE float->bf16
    union { float f; unsigned u; } c; c.f = f;
    unsigned r = (c.u + 0x7fff + ((c.u >> 16) & 1)) >> 16;
    return (short)r;
}
static __device__ __forceinline__ float bf2f(short b) {
    union { float f; unsigned u; } c;
    c.u = ((unsigned)(unsigned short)b) << 16;
    return c.f;
}

// ---- init: eT f32 [K][D], Bg bf16 [K][eh(64)|el(64)], e2 f32 (via f64) ------
__global__ void vq_init(const float* __restrict__ e, float* __restrict__ eT,
                        short* __restrict__ Bg, float* __restrict__ e2f,
                        float* __restrict__ loss_slot) {
    int idx = blockIdx.x * 256 + threadIdx.x;   // grid covers 32768
    if (idx < KCODES * DIM) {
        int k = idx >> 6, d = idx & 63;
        float v = e[d * KCODES + k];
        eT[k * DIM + d] = v;
        short hi = f2bf(v);
        float lo = v - bf2f(hi);                // exact (Sterbenz)
        Bg[k * 128 + d] = hi;
        Bg[k * 128 + 64 + d] = f2bf(lo);
    }
    if (idx < KCODES) {
        double s = 0.0;
        for (int d = 0; d < DIM; ++d) {
            double v = (double)e[d * KCODES + idx];
            s = fma(v, v, s);
        }
        e2f[idx] = (float)s;
    }
    if (idx == 0) *loss_slot = 0.f;
}

__global__ void vq_zero_loss(float* __restrict__ loss_slot) { *loss_slot = 0.f; }

// ---- wave-cooperative exact fp64 rescan of one row (all 64 lanes call) -----
__device__ inline void wave_rescan(const float* __restrict__ x,
                                   const float* __restrict__ e,  // [D][K]
                                   int row, double* outDist, int* outK) {
    const int lane = threadIdx.x & 63;
    const float* xr = x + (size_t)row * DIM;
    double x2d = 0.0;
    for (int d = 0; d < DIM; ++d) {
        double xd = (double)xr[d];
        x2d = fma(xd, xd, x2d);
    }
    double best = 1e300; int bk = 0;
    for (int j = 0; j < 8; ++j) {
        const int k = lane + (j << 6);
        double dot = 0.0, e2 = 0.0;
        for (int d = 0; d < DIM; ++d) {
            double xd = (double)xr[d];
            double ev = (double)e[d * KCODES + k];
            dot = fma(xd, ev, dot);
            e2 = fma(ev, ev, e2);
        }
        double dist = fma(-2.0, dot, x2d + e2);
        if (dist < best) { best = dist; bk = k; }
    }
    #pragma unroll
    for (int off = 32; off; off >>= 1) {
        double od = __shfl_xor(best, off);
        int ok = __shfl_xor(bk, off);
        if (od < best || (od == best && ok < bk)) { best = od; bk = ok; }
    }
    *outDist = best; *outK = bk;
}

// ---- main MFMA kernel: block=256 (4 waves), wave=32 rows, grid=N/128 -------
__global__ __launch_bounds__(256, 4) void vq_mfma(
    const float* __restrict__ x, const float* __restrict__ e,
    const float* __restrict__ eT, const short* __restrict__ Bg,
    const float* __restrict__ e2f,
    float* __restrict__ out, float* __restrict__ loss_slot) {

    __shared__ short shB[128 * 136];   // 128 codes x (128 bf16 + e2 f32 + pad) = 34816 B

    const int tid = threadIdx.x;
    const int lane = tid & 63;
    const int n = lane & 15;           // MFMA col / A-row index
    const int q = lane >> 4;           // quad
    const int wbase = blockIdx.x * 128 + (tid >> 6) * 32;

    // ---- A fragments (hi/lo) + C-layout x2 for 2 strips of 16 rows ----
    bf16x8 Ah0[2], Ah1[2], Al0[2], Al1[2];
    float x2c[2][4];
    #pragma unroll
    for (int s = 0; s < 2; ++s) {
        const int row = wbase + s * 16 + n;            // A-layout row = lane&15
        const float4* xr = (const float4*)(x + (size_t)row * DIM);
        float4 f0 = xr[2*q], f1 = xr[2*q+1], f2 = xr[8+2*q], f3 = xr[9+2*q];
        float v0s[8] = {f0.x,f0.y,f0.z,f0.w,f1.x,f1.y,f1.z,f1.w};   // dims 8q..8q+7
        float v1s[8] = {f2.x,f2.y,f2.z,f2.w,f3.x,f3.y,f3.z,f3.w};   // dims 32+8q..+7
        float p = 0.f;
        #pragma unroll
        for (int j = 0; j < 8; ++j) {
            float v0 = v0s[j], v1 = v1s[j];
            short h0 = f2bf(v0), h1 = f2bf(v1);
            Ah0[s][j] = h0;            Ah1[s][j] = h1;
            Al0[s][j] = f2bf(v0 - bf2f(h0));
            Al1[s][j] = f2bf(v1 - bf2f(h1));
            p = fmaf(v0, v0, p);
            p = fmaf(v1, v1, p);
        }
        p += __shfl_xor(p, 16);        // lanes {n, n+16, n+32, n+48} -> full x2
        p += __shfl_xor(p, 32);
        #pragma unroll
        for (int r = 0; r < 4; ++r)    // C-layout row 4q+r held by src lane 4q+r
            x2c[s][r] = __shfl(p, 4 * q + r);
    }

    float best[2][4], sec[2][4]; int bidx[2][4];
    #pragma unroll
    for (int s = 0; s < 2; ++s)
        #pragma unroll
        for (int r = 0; r < 4; ++r) { best[s][r] = 3.4e38f; sec[s][r] = 3.4e38f; bidx[s][r] = 0; }

    for (int stage = 0; stage < 4; ++stage) {
        const int hb = stage * 128;
        {   // stage 128 codes into LDS (stride 136 shorts = 272 B; e2 in pad)
            const int c0 = tid >> 4, qq = tid & 15;
            #pragma unroll
            for (int i = 0; i < 8; ++i) {
                int c = c0 + 16 * i;
                *(float4*)&shB[c * 136 + qq * 8] =
                    *(const float4*)&Bg[(size_t)(hb + c) * 128 + qq * 8];
                if (qq == 0) *(float*)&shB[c * 136 + 128] = e2f[hb + c];
            }
        }
        __syncthreads();

        for (int ch = 0; ch < 8; ++ch) {
            const int c = ch * 16 + n;
            const short* bp = &shB[c * 136 + q * 8];   // B[k=q*8+j][n], k contiguous
            bf16x8 Beh0 = *(const bf16x8*)(bp);
            bf16x8 Beh1 = *(const bf16x8*)(bp + 32);
            bf16x8 Bel0 = *(const bf16x8*)(bp + 64);
            bf16x8 Bel1 = *(const bf16x8*)(bp + 96);
            const float e2c = *(const float*)&shB[c * 136 + 128];
            const int kg = hb + ch * 16 + n;
            #pragma unroll
            for (int s = 0; s < 2; ++s) {
                f32x4 acc = {0.f, 0.f, 0.f, 0.f};
                acc = __builtin_amdgcn_mfma_f32_16x16x32_bf16(Ah0[s], Beh0, acc, 0, 0, 0);
                acc = __builtin_amdgcn_mfma_f32_16x16x32_bf16(Ah1[s], Beh1, acc, 0, 0, 0);
                acc = __builtin_amdgcn_mfma_f32_16x16x32_bf16(Ah0[s], Bel0, acc, 0, 0, 0);
                acc = __builtin_amdgcn_mfma_f32_16x16x32_bf16(Ah1[s], Bel1, acc, 0, 0, 0);
                acc = __builtin_amdgcn_mfma_f32_16x16x32_bf16(Al0[s], Beh0, acc, 0, 0, 0);
                acc = __builtin_amdgcn_mfma_f32_16x16x32_bf16(Al1[s], Beh1, acc, 0, 0, 0);
                acc = __builtin_amdgcn_mfma_f32_16x16x32_bf16(Al0[s], Bel0, acc, 0, 0, 0);
                acc = __builtin_amdgcn_mfma_f32_16x16x32_bf16(Al1[s], Bel1, acc, 0, 0, 0);
                #pragma unroll
                for (int r = 0; r < 4; ++r) {
                    float d = fmaf(-2.f, acc[r], x2c[s][r] + e2c);
                    if (d < best[s][r]) { sec[s][r] = best[s][r]; best[s][r] = d; bidx[s][r] = kg; }
                    else if (d < sec[s][r]) { sec[s][r] = d; }
                }
            }
        }
        __syncthreads();
    }

    // ---- cross-lane argmin merge over the 16 cols (groups of 16 lanes) ----
    #pragma unroll
    for (int off = 1; off <= 8; off <<= 1) {
        #pragma unroll
        for (int s = 0; s < 2; ++s)
            #pragma unroll
            for (int r = 0; r < 4; ++r) {
                float ob = __shfl_xor(best[s][r], off);
                float os = __shfl_xor(sec[s][r], off);
                int   oi = __shfl_xor(bidx[s][r], off);
                bool take = (ob < best[s][r]) || (ob == best[s][r] && oi < bidx[s][r]);
                float nb = take ? ob : best[s][r];
                int   ni = take ? oi : bidx[s][r];
                float ns = take ? fminf(best[s][r], os) : fminf(ob, sec[s][r]);
                best[s][r] = nb; bidx[s][r] = ni; sec[s][r] = ns;
            }
    }

    // ---- rare fp64 certify/rescan for rows with thin margin ----
    #pragma unroll
    for (int s = 0; s < 2; ++s)
        for (int r = 0; r < 4; ++r) {
            unsigned long long m =
                __ballot((sec[s][r] - best[s][r] < TAU_MFMA) && (n == 0));
            while (m) {
                int l = __builtin_ctzll(m);
                m &= m - 1;
                int qq = l >> 4;
                double bd; int bk;
                wave_rescan(x, e, wbase + s * 16 + 4 * qq + r, &bd, &bk);
                if (q == qq) { best[s][r] = (float)bd; bidx[s][r] = bk; }
            }
        }

    // ---- write quantized rows + loss ----
    float lp = 0.f;
    #pragma unroll
    for (int s = 0; s < 2; ++s)
        #pragma unroll
        for (int r = 0; r < 4; ++r) {
            int row = wbase + s * 16 + 4 * q + r;
            const float4* src = (const float4*)(eT + (size_t)bidx[s][r] * DIM);
            ((float4*)(out + (size_t)row * DIM))[n] = src[n];
            if (n == 0) lp += best[s][r];
        }
    #pragma unroll
    for (int off = 1; off < 64; off <<= 1) lp += __shfl_xor(lp, off);
    if (lane == 0)
        atomicAdd(loss_slot, lp * (1.25f / ((float)N_ROWS * (float)DIM)));
}

// ---- fallback (no workspace): round-3 scalar kernel, 2 rows/thread ---------
__global__ __launch_bounds__(256, 2) void vq_scalar(
    const float* __restrict__ x, const float* __restrict__ e,
    float* __restrict__ out, float* __restrict__ loss_slot) {

    __shared__ float sh[128 * 68];
    __shared__ float red[256];
    const int tid = threadIdx.x;
    const int blockBase = blockIdx.x * 512;
    const int r0 = blockBase + tid, r1 = r0 + 256;

    float xa[DIM], xb[DIM];
    {
        const float4* xr0 = (const float4*)(x + (size_t)r0 * DIM);
        const float4* xr1 = (const float4*)(x + (size_t)r1 * DIM);
        #pragma unroll
        for (int j = 0; j < 16; ++j) {
            float4 v0 = xr0[j], v1 = xr1[j];
            xa[4*j]=v0.x; xa[4*j+1]=v0.y; xa[4*j+2]=v0.z; xa[4*j+3]=v0.w;
            xb[4*j]=v1.x; xb[4*j+1]=v1.y; xb[4*j+2]=v1.z; xb[4*j+3]=v1.w;
        }
    }
    float x2a = 0.f, x2b = 0.f;
    #pragma unroll
    for (int d = 0; d < DIM; ++d) { x2a = fmaf(xa[d], xa[d], x2a); x2b = fmaf(xb[d], xb[d], x2b); }

    float bestA = 3.4e38f, secA = 3.4e38f, bestB = 3.4e38f, secB = 3.4e38f;
    int bkA = 0, bkB = 0;

    for (int kb = 0; kb < KCODES; kb += 128) {
        for (int idx = tid; idx < 128 * DIM; idx += 256) {
            int d = idx >> 7, c = idx & 127;
            sh[c * 68 + d] = e[d * KCODES + kb + c];
        }
        __syncthreads();
        if (tid < 128) {
            float ssum = 0.f;
            for (int d = 0; d < DIM; ++d) { float v = sh[tid * 68 + d]; ssum = fmaf(v, v, ssum); }
            sh[tid * 68 + 64] = ssum;
        }
        __syncthreads();
        for (int k = 0; k < 128; ++k) {
            const float* ck = sh + k * 68;
            float a0=0.f,a1=0.f,b0=0.f,b1=0.f;
            #pragma unroll
            for (int j = 0; j < 16; j += 2) {
                float4 c0 = *(const float4*)(ck + 4*j);
                float4 c1 = *(const float4*)(ck + 4*j + 4);
                a0=fmaf(xa[4*j],c0.x,a0); a0=fmaf(xa[4*j+1],c0.y,a0); a0=fmaf(xa[4*j+2],c0.z,a0); a0=fmaf(xa[4*j+3],c0.w,a0);
                b0=fmaf(xb[4*j],c0.x,b0); b0=fmaf(xb[4*j+1],c0.y,b0); b0=fmaf(xb[4*j+2],c0.z,b0); b0=fmaf(xb[4*j+3],c0.w,b0);
                a1=fmaf(xa[4*j+4],c1.x,a1); a1=fmaf(xa[4*j+5],c1.y,a1); a1=fmaf(xa[4*j+6],c1.z,a1); a1=fmaf(xa[4*j+7],c1.w,a1);
                b1=fmaf(xb[4*j+4],c1.x,b1); b1=fmaf(xb[4*j+5],c1.y,b1); b1=fmaf(xb[4*j+6],c1.z,b1); b1=fmaf(xb[4*j+7],c1.w,b1);
            }
            const float e2k = ck[64]; const int kg = kb + k;
            const float dA = fmaf(-2.f, a0 + a1, x2a + e2k);
            const float dB = fmaf(-2.f, b0 + b1, x2b + e2k);
            if (dA < bestA) { secA = bestA; bestA = dA; bkA = kg; } else if (dA < secA) secA = dA;
            if (dB < bestB) { secB = bestB; bestB = dB; bkB = kg; } else if (dB < secB) secB = dB;
        }
        __syncthreads();
    }

    const int lane = tid & 63;
    const int waveBase = blockBase + (tid & ~63);
    unsigned long long m = __ballot(secA - bestA < TAU_SC);
    while (m) {
        int l = __builtin_ctzll(m); m &= m - 1;
        double bd; int bk2;
        wave_rescan(x, e, waveBase + l, &bd, &bk2);
        if (lane == l) { bestA = (float)bd; bkA = bk2; }
    }
    m = __ballot(secB - bestB < TAU_SC);
    while (m) {
        int l = __builtin_ctzll(m); m &= m - 1;
        double bd; int bk2;
        wave_rescan(x, e, waveBase + 256 + l, &bd, &bk2);
        if (lane == l) { bestB = (float)bd; bkB = bk2; }
    }

    float4* o0 = (float4*)(out + (size_t)r0 * DIM);
    float4* o1 = (float4*)(out + (size_t)r1 * DIM);
    #pragma unroll
    for (int j = 0; j < 16; ++j) {
        float4 va, vb;
        va.x=e[(4*j)*KCODES+bkA]; vb.x=e[(4*j)*KCODES+bkB];
        va.y=e[(4*j+1)*KCODES+bkA]; vb.y=e[(4*j+1)*KCODES+bkB];
        va.z=e[(4*j+2)*KCODES+bkA]; vb.z=e[(4*j+2)*KCODES+bkB];
        va.w=e[(4*j+3)*KCODES+bkA]; vb.w=e[(4*j+3)*KCODES+bkB];
        o0[j]=va; o1[j]=vb;
    }

    red[tid] = bestA + bestB;
    __syncthreads();
    #pragma unroll
    for (int s2 = 128; s2 > 0; s2 >>= 1) {
        if (tid < s2) red[tid] += red[tid + s2];
        __syncthreads();
    }
    if (tid == 0) atomicAdd(loss_slot, red[0] * (1.25f / ((float)N_ROWS * (float)DIM)));
}

extern "C" void kernel_launch(void* const* d_in, const int* in_sizes, int n_in,
                              void* d_out, int out_size, void* d_ws, size_t ws_size,
                              hipStream_t stream) {
    const float* x = (const float*)d_in[0];   // [N, D]
    const float* e = (const float*)d_in[1];   // [D, K]
    float* out = (float*)d_out;               // N*D quantized + 1 loss
    float* loss_slot = out + (size_t)N_ROWS * DIM;

    // ws layout: eT f32 [512][64] @0 (131072 B) | Bg bf16 [512][128] @131072 | e2f @262144
    const size_t ws_needed = 131072 + 131072 + KCODES * sizeof(float);

    if (ws_size >= ws_needed) {
        float* eT = (float*)d_ws;
        short* Bg = (short*)((char*)d_ws + 131072);
        float* e2f = (float*)((char*)d_ws + 262144);
        vq_init<<<128, 256, 0, stream>>>(e, eT, Bg, e2f, loss_slot);
        vq_mfma<<<N_ROWS / 128, 256, 0, stream>>>(x, e, eT, Bg, e2f, out, loss_slot);
    } else {
        vq_zero_loss<<<1, 1, 0, stream>>>(loss_slot);
        vq_scalar<<<N_ROWS / 512, 256, 0, stream>>>(x, e, out, loss_slot);
    }
}